// Round 20
// baseline (242.200 us; speedup 1.0000x reference)
//
#include <hip/hip_runtime.h>
#include <math.h>

#define HH 512
#define WW 512
#define HW (HH * WW)
#define PW 514                    // padded width/height
#define PPIX (PW * PW)

#define A_U    18432              // 32co*9off*64ci ushorts = 36864 B
#define B0_U   18432              // buffer0 start (ushorts)
#define B1_U   29696              // buffer1 start (= 18432 + 11264)
#define B_ALLOC 11264             // 22 loads x 512 ushorts (10880 used + pad)
#define LDS_BYTES 81920           // EXACT half of the 160 KiB pool -> 2 blocks/CU

typedef short bf16x8 __attribute__((ext_vector_type(8)));
typedef float f32x4  __attribute__((ext_vector_type(4)));
typedef float f32x16 __attribute__((ext_vector_type(16)));

__device__ __forceinline__ ushort f2bf(float f) {
    union { float f; uint u; } c; c.f = f;
    uint u = c.u;
    return (ushort)((u + 0x7fffu + ((u >> 16) & 1u)) >> 16);
}

__device__ __forceinline__ uint cvtpk(float a, float b) {
    uint r;
    asm("v_cvt_pk_bf16_f32 %0, %1, %2" : "=v"(r) : "v"(a), "v"(b));
    return r;
}

// ---------------- kernel 1: styles ----------------
__global__ void k_styles(const float* __restrict__ wsv, const float* __restrict__ aw,
                         const float* __restrict__ ab, float* __restrict__ styles) {
    int bid = blockIdx.x;
    int b = bid >> 6, ci = bid & 63;
    int l = threadIdx.x;
    const float* wrow = wsv + b * 512;
    const float* arow = aw + ci * 512;
    float s = 0.f;
    #pragma unroll
    for (int j = 0; j < 8; ++j)
        s += wrow[l + 64 * j] * arow[l + 64 * j];
    #pragma unroll
    for (int off = 32; off; off >>= 1)
        s += __shfl_xor(s, off, 64);
    if (l == 0)
        styles[b * 64 + ci] = s * 0.044194173824159216f + ab[ci];
}

// ------------- kernel 2: modulate+demodulate -> bf16 [b][co][off 9][ci 64] -------------
// ci-group (ci>>3) stored XORed with (co&7): conflict-free weight ds_reads after a
// purely LINEAR global_load_lds stage (swizzle baked at write time). (R8/R10-proven)
__global__ void k_wmod(const float* __restrict__ cw, const float* __restrict__ styles,
                       ushort* __restrict__ wb) {
    int b = blockIdx.x >> 6, co = blockIdx.x & 63;
    int ci = threadIdx.x;
    float st = styles[b * 64 + ci];
    const float* wp = cw + (co * 64 + ci) * 9;
    float wv[9];
    float ss = 0.f;
    #pragma unroll
    for (int k = 0; k < 9; ++k) { wv[k] = wp[k] * st; ss += wv[k] * wv[k]; }
    #pragma unroll
    for (int off = 32; off; off >>= 1)
        ss += __shfl_xor(ss, off, 64);
    float dm = 1.0f / sqrtf(ss + 1e-8f);
    int cisw = ((((ci >> 3) ^ co) & 7) << 3) | (ci & 7);
    #pragma unroll
    for (int k = 0; k < 9; ++k)
        wb[((size_t)(b * 64 + co) * 9 + k) * 64 + cisw] = f2bf(wv[k] * dm);
}

// ------------- kernel 2c: x fp32 NCHW -> xp bf16 [b][gy+1][gx+1][ci], pad fused -------------
__global__ __launch_bounds__(256) void k_xpose(
    const float* __restrict__ x, ushort* __restrict__ xp) {
    const int t = threadIdx.x;
    const int bid = blockIdx.x;

    if (bid >= 8192) {            // ---- fused zeropad of the border ----
        int id = (bid - 8192) * 256 + t;
        if (id >= 4 * 2052) return;
        int b = id / 2052, r = id % 2052;
        int gyp, gxp;
        if (r < 514)       { gyp = 0;        gxp = r; }
        else if (r < 1028) { gyp = 513;      gxp = r - 514; }
        else if (r < 1540) { gyp = r - 1027; gxp = 0; }
        else               { gyp = r - 1539; gxp = 513; }
        ushort* p = xp + (((size_t)b * PW + gyp) * PW + gxp) * 64;
        uint4 z = make_uint4(0, 0, 0, 0);
        #pragma unroll
        for (int i = 0; i < 8; ++i) *(uint4*)(p + i * 8) = z;
        return;
    }

    __shared__ ushort lt[128 * 68];
    const int gxt = bid & 3;
    const int gy  = (bid >> 2) & 511;
    const int b   = bid >> 11;

    const float* xb = x + (size_t)b * 64 * HW + (size_t)gy * WW + gxt * 128;
    const int ci0 = 8 * (t >> 5);
    const int gxc = t & 31;

    f32x4 v[8];
    #pragma unroll
    for (int j = 0; j < 8; ++j)
        v[j] = *(const f32x4*)(xb + (size_t)(ci0 + j) * HW + gxc * 4);

    #pragma unroll
    for (int p = 0; p < 4; ++p) {
        int px = gxc * 4 + p;
        int rowp = ((px & 3) * 32 + (px >> 2)) * 68;
        #pragma unroll
        for (int cg = 0; cg < 2; ++cg) {
            uint lo = cvtpk(v[4 * cg + 0][p], v[4 * cg + 1][p]);
            uint hi = cvtpk(v[4 * cg + 2][p], v[4 * cg + 3][p]);
            *(uint2*)&lt[rowp + ci0 + 4 * cg] = make_uint2(lo, hi);
        }
    }
    __syncthreads();

    const int px = t >> 1, half = t & 1;
    const int rowp = ((px & 3) * 32 + (px >> 2)) * 68 + half * 32;
    uint4 o0 = *(uint4*)&lt[rowp + 0];
    uint4 o1 = *(uint4*)&lt[rowp + 8];
    uint4 o2 = *(uint4*)&lt[rowp + 16];
    uint4 o3 = *(uint4*)&lt[rowp + 24];
    ushort* dst = xp + (((size_t)b * PW + (gy + 1)) * PW + (gxt * 128 + px + 1)) * 64
                     + half * 32;
    *(uint4*)(dst + 0)  = o0;
    *(uint4*)(dst + 8)  = o1;
    *(uint4*)(dst + 16) = o2;
    *(uint4*)(dst + 24) = o3;
}

// ------------- kernel 3: persistent MFMA conv, 2 BLOCKS/CU (co-split + K-split) -------------
// 512 blocks (2/CU), 256 threads (4 waves). Block = (b, coh: 32 co, band: 8 rows).
// LDS/block = A(32co, 36KB) + 2 x B-half([10r][34c][32ci], 22KB+pad) = EXACTLY 80KB
// -> 2 independent blocks per CU whose stage/compute/store phases overlap (m114) --
// the mechanism R17's intra-block TLP could not provide (per-tile barriers lockstep
// all waves of one block, but not blocks).
// B swizzle (4-slot analog of the R8-proven 8-slot): slot=(2kb+hl)^(lcol&3), baked
// into the staged SOURCE address; read applies ^(kb<<4) exactly as R19.
// Pipeline/tile: noise -> stage(h1)->buf1 -> stores(prev) -> compute h0 ->
// vmcnt(32)+bar -> stage(next,h0)->buf0 -> compute h1 (acc carries K) ->
// transform acc -> vmcnt(0)+bar.  Stores stay in flight across the mid barrier.
__global__ __launch_bounds__(256) void k_conv(
    const ushort* __restrict__ xp,    // [4][514][514][64] bf16 padded
    const ushort* __restrict__ wb,    // [4][64co][9][64ci] bf16 (swizzle baked)
    const float* __restrict__ noise,  // [4][1][512][512]
    const float* __restrict__ bias,   // [64]
    float* __restrict__ out) {        // [4][64][512][512] fp32
    extern __shared__ __align__(16) ushort lds[];

    const int t = threadIdx.x;
    const int w = t >> 6;                // wave 0..3 = row-pair
    const int lane = t & 63;
    const int n5 = lane & 31;            // MFMA N/M lane coord
    const int hl = lane >> 5;            // k-subgroup (8 ci)
    const int blk = blockIdx.x;
    const int b   = blk >> 7;
    const int coh = (blk >> 6) & 1;      // co half (co-pair blocks are 64 apart -> same XCD)
    const int j64 = blk & 63;
    const int band = (j64 & 7) * 8 + (j64 >> 3);   // T1: XCD j64&7 owns bands 8k..8k+7
    const int ty = band * 8;

    const ushort* xpb = xp + (size_t)b * PPIX * 64;
    const ushort* wA  = wb + (size_t)(b * 64 + coh * 32) * 576;

    // ---- stage A once: 36 x 1KB linear copy (32 co) ----
    #pragma unroll
    for (int jj = 0; jj < 9; ++jj) {
        int j = w + jj * 4;
        const ushort* src = wA + j * 512 + lane * 8;
        __builtin_amdgcn_global_load_lds(
            (const __attribute__((address_space(1))) unsigned int*)src,
            (__attribute__((address_space(3))) unsigned int*)&lds[j * 512],
            16, 0, 0);
    }

    // ---- B staging source offsets (tile/h-invariant part) ----
    int soff[6];
    #pragma unroll
    for (int jj = 0; jj < 6; ++jj) {
        int j = w + jj * 4;
        if (j < 22) {
            int u = j * 512 + lane * 8;
            int u2 = u < 10872 ? u : 10872;   // tail clamp (src only; dst stays linear)
            int pxl = u2 >> 5;                // 32 ushorts per px
            int cig = (u2 >> 3) & 3;          // slot within the 32-ci half
            int row = pxl / 34;
            int lcol = pxl - row * 34;
            int gsrc = cig ^ (lcol & 3);      // pre-swizzled source ci-group (4-slot)
            soff[jj] = ((ty + row) * PW + lcol) * 64 + gsrc * 8;
        } else soff[jj] = 0;
    }

    // stage one 32-ci half of a B tile into buffer at bufu
    auto stage_b = [&](int bufu, int txn, int h) {
        #pragma unroll
        for (int jj = 0; jj < 6; ++jj) {
            int j = w + jj * 4;
            if (j < 22)
                __builtin_amdgcn_global_load_lds(
                    (const __attribute__((address_space(1))) unsigned int*)
                        (xpb + soff[jj] + txn * 64 + h * 32),
                    (__attribute__((address_space(3))) unsigned int*)
                        &lds[bufu + j * 512],
                    16, 0, 0);
        }
    };

    // ---- prologue: stage (tile0, h0) into buf0 ----
    stage_b(B0_U, 0, 0);
    asm volatile("s_waitcnt vmcnt(0)" ::: "memory");
    __syncthreads();

    // ---- A read base (R19 formula, 32-co region) ----
    const int aidx = n5 * 576 + ((hl ^ (n5 & 7)) << 3);

    // ---- B read bases: row = 2w + (n5>>4), col = i*16 + (n5&15) + dx ----
    int bidx[2][3];
    const int brow = 2 * w + (n5 >> 4);
    #pragma unroll
    for (int i = 0; i < 2; ++i)
        #pragma unroll
        for (int dx = 0; dx < 3; ++dx) {
            int lcol = i * 16 + (n5 & 15) + dx;
            bidx[i][dx] = (brow * 34 + lcol) * 32 + ((hl ^ (lcol & 3)) << 3);
        }

    const float* nz = noise + (size_t)b * HW;
    const int orow = ty + brow;           // output row for this lane
    const size_t outb = (size_t)(b * 64 + coh * 32) * HW;

    f32x16 acc[2];

    for (int it = 0; it < 16; ++it) {
        const int tx = it * 32;

        // noise loads (oldest vmem of this iter)
        float nv[2];
        #pragma unroll
        for (int i = 0; i < 2; ++i)
            nv[i] = nz[orow * WW + tx + i * 16 + (n5 & 15)];

        // stage (it, h1) -> buf1 (buf1 free since prev tile's barrier)
        stage_b(B1_U, tx, 1);

        // stores for tile it-1 (values already transformed in acc) -- youngest vmem
        if (it > 0) {
            const int ptx = tx - 32;
            #pragma unroll
            for (int i = 0; i < 2; ++i) {
                const int ocol = ptx + i * 16 + (n5 & 15);
                #pragma unroll
                for (int reg = 0; reg < 16; ++reg) {
                    int co = (reg & 3) + 8 * (reg >> 2) + 4 * hl;
                    out[outb + (size_t)co * HW + (size_t)orow * WW + ocol] = acc[i][reg];
                }
            }
        }

        // ---- compute h0 from buf0 (kb_global 0,1) ----
        #pragma unroll
        for (int i = 0; i < 2; ++i)
            acc[i] = (f32x16){0.f,0.f,0.f,0.f,0.f,0.f,0.f,0.f,
                              0.f,0.f,0.f,0.f,0.f,0.f,0.f,0.f};
        #pragma unroll
        for (int dy = 0; dy < 3; ++dy) {
            #pragma unroll
            for (int dx = 0; dx < 3; ++dx) {
                const int off = dy * 3 + dx;
                #pragma unroll
                for (int kb = 0; kb < 2; ++kb) {
                    bf16x8 afr = *(const bf16x8*)
                        &lds[(aidx + off * 64) ^ (kb << 4)];          // kbg = kb
                    #pragma unroll
                    for (int i = 0; i < 2; ++i) {
                        bf16x8 bfr = *(const bf16x8*)
                            &lds[B0_U + ((bidx[i][dx] + dy * (34 * 32)) ^ (kb << 4))];
                        acc[i] = __builtin_amdgcn_mfma_f32_32x32x16_bf16(
                            afr, bfr, acc[i], 0, 0, 0);
                    }
                }
            }
        }

        // boundary A: retire noise+stage(h1); leave stores in flight
        if (it == 0) { asm volatile("s_waitcnt vmcnt(0)" ::: "memory"); }
        else         { asm volatile("s_waitcnt vmcnt(32)" ::: "memory"); }
        __builtin_amdgcn_sched_barrier(0);
        __builtin_amdgcn_s_barrier();

        // stage (it+1, h0) -> buf0 (safe: all waves past compute h0)
        if (it < 15) stage_b(B0_U, tx + 32, 0);

        // ---- compute h1 from buf1 (kb_global 2,3), accumulate ----
        #pragma unroll
        for (int dy = 0; dy < 3; ++dy) {
            #pragma unroll
            for (int dx = 0; dx < 3; ++dx) {
                const int off = dy * 3 + dx;
                #pragma unroll
                for (int kb = 0; kb < 2; ++kb) {
                    bf16x8 afr = *(const bf16x8*)
                        &lds[(aidx + off * 64) ^ ((2 + kb) << 4)];    // kbg = 2+kb
                    #pragma unroll
                    for (int i = 0; i < 2; ++i) {
                        bf16x8 bfr = *(const bf16x8*)
                            &lds[B1_U + ((bidx[i][dx] + dy * (34 * 32)) ^ (kb << 4))];
                        acc[i] = __builtin_amdgcn_mfma_f32_32x32x16_bf16(
                            afr, bfr, acc[i], 0, 0, 0);
                    }
                }
            }
        }

        // ---- transform in place: +noise, +bias, lrelu*sqrt2, clamp ----
        // C layout (m74/m101): col = lane&31 (px), row = (reg&3)+8*(reg>>2)+4*hl (co)
        #pragma unroll
        for (int i = 0; i < 2; ++i) {
            #pragma unroll
            for (int reg = 0; reg < 16; ++reg) {
                int co = (reg & 3) + 8 * (reg >> 2) + 4 * hl;
                float y = acc[i][reg] + nv[i] + bias[coh * 32 + co];
                y = (y >= 0.f ? y : 0.2f * y) * 1.41421356237f;
                y = fminf(fmaxf(y, -256.f), 256.f);
                acc[i][reg] = y;
            }
        }

        // boundary B: retire stage(it+1,h0) (youngest) -> full drain; stores of
        // it-1 have had both compute phases to drain.
        asm volatile("s_waitcnt vmcnt(0)" ::: "memory");
        __builtin_amdgcn_sched_barrier(0);
        __builtin_amdgcn_s_barrier();
    }

    // ---- final stores (tile 15) ----
    {
        const int ptx = 15 * 32;
        #pragma unroll
        for (int i = 0; i < 2; ++i) {
            const int ocol = ptx + i * 16 + (n5 & 15);
            #pragma unroll
            for (int reg = 0; reg < 16; ++reg) {
                int co = (reg & 3) + 8 * (reg >> 2) + 4 * hl;
                out[outb + (size_t)co * HW + (size_t)orow * WW + ocol] = acc[i][reg];
            }
        }
    }
}

extern "C" void kernel_launch(void* const* d_in, const int* in_sizes, int n_in,
                              void* d_out, int out_size, void* d_ws, size_t ws_size,
                              hipStream_t stream) {
    const float* x     = (const float*)d_in[0];
    const float* wsv   = (const float*)d_in[1];
    const float* noise = (const float*)d_in[2];
    const float* aw    = (const float*)d_in[3];
    const float* ab    = (const float*)d_in[4];
    const float* cw    = (const float*)d_in[5];
    const float* bias  = (const float*)d_in[6];
    float* out = (float*)d_out;

    float*  styles = (float*)d_ws;                          // 1 KB
    ushort* wb16   = (ushort*)((char*)d_ws + 1024);         // 294912 B
    ushort* xpad   = (ushort*)((char*)d_ws + (1 << 20));    // 135.3 MB

    hipFuncSetAttribute((const void*)k_conv,
                        hipFuncAttributeMaxDynamicSharedMemorySize, LDS_BYTES);

    k_styles<<<256, 64, 0, stream>>>(wsv, aw, ab, styles);
    k_wmod<<<256, 64, 0, stream>>>(cw, styles, wb16);
    k_xpose<<<8225, 256, 0, stream>>>(x, xpad);
    k_conv<<<512, 256, LDS_BYTES, stream>>>(xpad, wb16, noise, bias, out);
}